// Round 1
// baseline (573.394 us; speedup 1.0000x reference)
//
#include <hip/hip_runtime.h>

#define DIN 2048
#define DOUT 2048
#define NHEADS 16
#define HDIM 128
#define LATENT 256
#define BB 2
#define SS 2048
#define MTOT (BB*SS)

using bf16 = __bf16;
using bf16x8 = __attribute__((ext_vector_type(8))) __bf16;
using f32x4 = __attribute__((ext_vector_type(4))) float;

// ---------------- cast fp32 -> bf16 (vectorized) ----------------
__global__ void cast_f32_bf16(const float* __restrict__ in, bf16* __restrict__ out, int n) {
    int i = (blockIdx.x * blockDim.x + threadIdx.x) * 8;
    if (i >= n) return;
    float4 a = *(const float4*)(in + i);
    float4 b = *(const float4*)(in + i + 4);
    bf16x8 o;
    o[0] = (bf16)a.x; o[1] = (bf16)a.y; o[2] = (bf16)a.z; o[3] = (bf16)a.w;
    o[4] = (bf16)b.x; o[5] = (bf16)b.y; o[6] = (bf16)b.z; o[7] = (bf16)b.w;
    *(bf16x8*)(out + i) = o;
}

// ---------------- transpose + cast: W[R][C] fp32 -> WT[C][R] bf16 ----------------
__global__ void transpose_cast(const float* __restrict__ W, bf16* __restrict__ WT, int R, int C) {
    __shared__ float tile[32][33];
    int c0 = blockIdx.x * 32, r0 = blockIdx.y * 32;
    int tx = threadIdx.x & 31, ty = threadIdx.x >> 5;  // 256 threads: ty 0..7
    #pragma unroll
    for (int i = ty; i < 32; i += 8)
        tile[i][tx] = W[(size_t)(r0 + i) * C + c0 + tx];
    __syncthreads();
    #pragma unroll
    for (int i = ty; i < 32; i += 8)
        WT[(size_t)(c0 + i) * R + r0 + tx] = (bf16)tile[tx][i];
}

// ---------------- transpose v[b*S+s][h*128+d] -> vT[b][h][d][s] (bf16) ----------------
__global__ void transpose_v(const bf16* __restrict__ v, bf16* __restrict__ vT) {
    int bh = blockIdx.z;
    int s0 = blockIdx.x * 32, d0 = blockIdx.y * 32;
    __shared__ bf16 t[32][33];
    int tx = threadIdx.x & 31, ty = threadIdx.x >> 5;
    int b = bh >> 4, h = bh & 15;
    #pragma unroll
    for (int i = ty; i < 32; i += 8)
        t[i][tx] = v[(size_t)(b * SS + s0 + i) * DOUT + h * HDIM + d0 + tx];
    __syncthreads();
    #pragma unroll
    for (int i = ty; i < 32; i += 8)
        vT[((size_t)bh * HDIM + d0 + i) * SS + s0 + tx] = t[tx][i];
}

// ---------------- GEMM: C[M][N] = A[M][K] @ BT[N][K]^T (+bias), bf16 in, bf16/f32 out ----------------
// 128x128 block tile, 4 waves (2x2), each wave 64x64 via 4x4 frags of 16x16x32 MFMA.
template<bool OUT_F32, bool BIAS>
__global__ __launch_bounds__(256) void gemm_bt(const bf16* __restrict__ A,
        const bf16* __restrict__ BT, void* __restrict__ Cp,
        const float* __restrict__ bias, const int Kdim, const int Ndim) {
    const int n0 = blockIdx.x * 128, m0 = blockIdx.y * 128;
    const int tid = threadIdx.x, wave = tid >> 6, lane = tid & 63;
    const int wm = wave >> 1, wn = wave & 1;
    const int lr = lane & 15, lg = lane >> 4;
    __shared__ __align__(16) bf16 As[128][40];  // pad +8: 2-way banks only
    __shared__ __align__(16) bf16 Bs[128][40];
    f32x4 acc[4][4];
    #pragma unroll
    for (int i = 0; i < 4; ++i)
        #pragma unroll
        for (int j = 0; j < 4; ++j) acc[i][j] = (f32x4){0.f, 0.f, 0.f, 0.f};

    const int row = tid >> 1, cs = (tid & 1) * 16;
    const bf16* ga = A + (size_t)(m0 + row) * Kdim + cs;
    const bf16* gb = BT + (size_t)(n0 + row) * Kdim + cs;

    for (int k0 = 0; k0 < Kdim; k0 += 32) {
        *(bf16x8*)&As[row][cs]     = *(const bf16x8*)(ga);
        *(bf16x8*)&As[row][cs + 8] = *(const bf16x8*)(ga + 8);
        *(bf16x8*)&Bs[row][cs]     = *(const bf16x8*)(gb);
        *(bf16x8*)&Bs[row][cs + 8] = *(const bf16x8*)(gb + 8);
        ga += 32; gb += 32;
        __syncthreads();
        bf16x8 af[4], bfr[4];
        #pragma unroll
        for (int i = 0; i < 4; ++i)
            af[i] = *(const bf16x8*)&As[wm * 64 + i * 16 + lr][lg * 8];
        #pragma unroll
        for (int j = 0; j < 4; ++j)
            bfr[j] = *(const bf16x8*)&Bs[wn * 64 + j * 16 + lr][lg * 8];
        #pragma unroll
        for (int i = 0; i < 4; ++i)
            #pragma unroll
            for (int j = 0; j < 4; ++j)
                acc[i][j] = __builtin_amdgcn_mfma_f32_16x16x32_bf16(af[i], bfr[j], acc[i][j], 0, 0, 0);
        __syncthreads();
    }
    #pragma unroll
    for (int i = 0; i < 4; ++i)
        #pragma unroll
        for (int j = 0; j < 4; ++j) {
            const int r0 = m0 + wm * 64 + i * 16 + lg * 4;
            const int c = n0 + wn * 64 + j * 16 + lr;
            #pragma unroll
            for (int r2 = 0; r2 < 4; ++r2) {
                float v = acc[i][j][r2];
                if (BIAS) v += bias[c];
                if (OUT_F32) ((float*)Cp)[(size_t)(r0 + r2) * Ndim + c] = v;
                else         ((bf16*)Cp)[(size_t)(r0 + r2) * Ndim + c] = (bf16)v;
            }
        }
}

// ---------------- causal flash attention ----------------
// grid (S/64, B*H); 4 waves, each owns 16 q-rows. K-tile = 64 rows.
__global__ __launch_bounds__(256) void attn_kernel(const bf16* __restrict__ q,
        const bf16* __restrict__ k, const bf16* __restrict__ vT, bf16* __restrict__ ctx) {
    const int bh = blockIdx.y, b = bh >> 4, h = bh & 15;
    const int q0 = blockIdx.x * 64;
    const int tid = threadIdx.x, wave = tid >> 6, lane = tid & 63;
    const int lr = lane & 15, lg = lane >> 4;
    __shared__ __align__(16) bf16 Ks[64][HDIM + 8];   // [kc][d]
    __shared__ __align__(16) bf16 Vs[HDIM][64 + 8];   // [d][kc]
    __shared__ __align__(16) bf16 Ps[64][64 + 8];     // [qr][kc], per-wave strips

    bf16x8 qf[4];
    const bf16* qbase = q + ((size_t)(b * SS + q0 + wave * 16 + lr)) * DOUT + h * HDIM;
    #pragma unroll
    for (int d = 0; d < 4; ++d) qf[d] = *(const bf16x8*)(qbase + d * 32 + lg * 8);

    f32x4 o[8];
    #pragma unroll
    for (int i = 0; i < 8; ++i) o[i] = (f32x4){0.f, 0.f, 0.f, 0.f};
    float m_i[4], l_i[4];
    #pragma unroll
    for (int r = 0; r < 4; ++r) { m_i[r] = -__builtin_inff(); l_i[r] = 0.f; }
    const float scale = 0.088388347648318447f;  // 1/sqrt(128)

    const int nkt = blockIdx.x + 1;
    for (int kt = 0; kt < nkt; ++kt) {
        const int kbase = kt * 64;
        {   // stage K tile (64x128) and V^T tile (128x64)
            int krow = tid >> 2, kcs = (tid & 3) * 32;
            const bf16* gk = k + ((size_t)(b * SS + kbase + krow)) * DOUT + h * HDIM + kcs;
            #pragma unroll
            for (int u = 0; u < 4; ++u)
                *(bf16x8*)&Ks[krow][kcs + u * 8] = *(const bf16x8*)(gk + u * 8);
            int vr = tid >> 1, vcs = (tid & 1) * 32;
            const bf16* gv = vT + ((size_t)bh * HDIM + vr) * SS + kbase + vcs;
            #pragma unroll
            for (int u = 0; u < 4; ++u)
                *(bf16x8*)&Vs[vr][vcs + u * 8] = *(const bf16x8*)(gv + u * 8);
        }
        __syncthreads();

        // S = Q @ K^T  (16 q-rows x 64 kc per wave)
        f32x4 sacc[4];
        #pragma unroll
        for (int nf = 0; nf < 4; ++nf) sacc[nf] = (f32x4){0.f, 0.f, 0.f, 0.f};
        #pragma unroll
        for (int nf = 0; nf < 4; ++nf)
            #pragma unroll
            for (int d = 0; d < 4; ++d) {
                bf16x8 kf = *(const bf16x8*)&Ks[nf * 16 + lr][d * 32 + lg * 8];
                sacc[nf] = __builtin_amdgcn_mfma_f32_16x16x32_bf16(qf[d], kf, sacc[nf], 0, 0, 0);
            }

        float sv[4][4];
        const bool maskt = (kbase + 63 > q0);  // only the diagonal tile
        #pragma unroll
        for (int nf = 0; nf < 4; ++nf)
            #pragma unroll
            for (int r = 0; r < 4; ++r) {
                float s = sacc[nf][r] * scale;
                if (maskt) {
                    int qr = q0 + wave * 16 + lg * 4 + r;
                    int kc = kbase + nf * 16 + lr;
                    if (qr < kc) s = -__builtin_inff();
                }
                sv[nf][r] = s;
            }
        // online softmax: row groups are 16 consecutive lanes (same lg)
        float corr[4];
        #pragma unroll
        for (int r = 0; r < 4; ++r) {
            float v = fmaxf(fmaxf(sv[0][r], sv[1][r]), fmaxf(sv[2][r], sv[3][r]));
            #pragma unroll
            for (int off = 1; off < 16; off <<= 1) v = fmaxf(v, __shfl_xor(v, off));
            float mnew = fmaxf(m_i[r], v);
            corr[r] = __expf(m_i[r] - mnew);
            m_i[r] = mnew;
        }
        float rsum[4] = {0.f, 0.f, 0.f, 0.f};
        #pragma unroll
        for (int nf = 0; nf < 4; ++nf)
            #pragma unroll
            for (int r = 0; r < 4; ++r) {
                float p = __expf(sv[nf][r] - m_i[r]);
                rsum[r] += p;
                Ps[wave * 16 + lg * 4 + r][nf * 16 + lr] = (bf16)p;
            }
        #pragma unroll
        for (int r = 0; r < 4; ++r) {
            float v = rsum[r];
            #pragma unroll
            for (int off = 1; off < 16; off <<= 1) v += __shfl_xor(v, off);
            l_i[r] = l_i[r] * corr[r] + v;
        }
        #pragma unroll
        for (int df = 0; df < 8; ++df)
            #pragma unroll
            for (int r = 0; r < 4; ++r) o[df][r] *= corr[r];

        // O += P @ V   (P from own wave's LDS strip; intra-wave ds ordering suffices)
        #pragma unroll
        for (int ks = 0; ks < 2; ++ks) {
            bf16x8 pf = *(const bf16x8*)&Ps[wave * 16 + lr][ks * 32 + lg * 8];
            #pragma unroll
            for (int df = 0; df < 8; ++df) {
                bf16x8 vf = *(const bf16x8*)&Vs[df * 16 + lr][ks * 32 + lg * 8];
                o[df] = __builtin_amdgcn_mfma_f32_16x16x32_bf16(pf, vf, o[df], 0, 0, 0);
            }
        }
        __syncthreads();
    }

    #pragma unroll
    for (int df = 0; df < 8; ++df)
        #pragma unroll
        for (int r = 0; r < 4; ++r) {
            int rrow = q0 + wave * 16 + lg * 4 + r;
            int col = h * HDIM + df * 16 + lr;
            ctx[(size_t)(b * SS + rrow) * DOUT + col] = (bf16)(o[df][r] / l_i[r]);
        }
}

extern "C" void kernel_launch(void* const* d_in, const int* in_sizes, int n_in,
                              void* d_out, int out_size, void* d_ws, size_t ws_size,
                              hipStream_t stream) {
    const float* x    = (const float*)d_in[0];
    const float* Wq   = (const float*)d_in[1];
    const float* Wdkv = (const float*)d_in[2];
    const float* Wuk  = (const float*)d_in[3];
    const float* Wuv  = (const float*)d_in[4];
    const float* Wout = (const float*)d_in[5];
    const float* bout = (const float*)d_in[6];

    char* ws = (char*)d_ws;
    size_t off = 0;
    auto alloc = [&](size_t bytes) { char* p = ws + off; off = (off + bytes + 255) & ~255ULL; return p; };
    bf16* xb    = (bf16*)alloc((size_t)MTOT * DIN * 2);
    bf16* WqT   = (bf16*)alloc((size_t)DOUT * DIN * 2);
    bf16* WdkvT = (bf16*)alloc((size_t)LATENT * DIN * 2);
    bf16* WukT  = (bf16*)alloc((size_t)DOUT * LATENT * 2);
    bf16* WuvT  = (bf16*)alloc((size_t)DOUT * LATENT * 2);
    bf16* WoutT = (bf16*)alloc((size_t)DOUT * DOUT * 2);
    bf16* qb    = (bf16*)alloc((size_t)MTOT * DOUT * 2);
    bf16* lat   = (bf16*)alloc((size_t)MTOT * LATENT * 2);
    bf16* kb    = (bf16*)alloc((size_t)MTOT * DOUT * 2);
    bf16* vb    = (bf16*)alloc((size_t)MTOT * DOUT * 2);
    bf16* vT    = (bf16*)alloc((size_t)BB * NHEADS * HDIM * SS * 2);
    bf16* ctx   = (bf16*)alloc((size_t)MTOT * DOUT * 2);

    cast_f32_bf16<<<(MTOT * DIN) / 8 / 256, 256, 0, stream>>>(x, xb, MTOT * DIN);
    transpose_cast<<<dim3(DOUT / 32, DIN / 32), 256, 0, stream>>>(Wq, WqT, DIN, DOUT);
    transpose_cast<<<dim3(LATENT / 32, DIN / 32), 256, 0, stream>>>(Wdkv, WdkvT, DIN, LATENT);
    transpose_cast<<<dim3(DOUT / 32, LATENT / 32), 256, 0, stream>>>(Wuk, WukT, LATENT, DOUT);
    transpose_cast<<<dim3(DOUT / 32, LATENT / 32), 256, 0, stream>>>(Wuv, WuvT, LATENT, DOUT);
    transpose_cast<<<dim3(DOUT / 32, DOUT / 32), 256, 0, stream>>>(Wout, WoutT, DOUT, DOUT);

    gemm_bt<false, false><<<dim3(DOUT / 128, MTOT / 128), 256, 0, stream>>>(xb, WqT, qb, nullptr, DIN, DOUT);
    gemm_bt<false, false><<<dim3(LATENT / 128, MTOT / 128), 256, 0, stream>>>(xb, WdkvT, lat, nullptr, DIN, LATENT);
    gemm_bt<false, false><<<dim3(DOUT / 128, MTOT / 128), 256, 0, stream>>>(lat, WukT, kb, nullptr, LATENT, DOUT);
    gemm_bt<false, false><<<dim3(DOUT / 128, MTOT / 128), 256, 0, stream>>>(lat, WuvT, vb, nullptr, LATENT, DOUT);

    transpose_v<<<dim3(SS / 32, HDIM / 32, BB * NHEADS), 256, 0, stream>>>(vb, vT);

    attn_kernel<<<dim3(SS / 64, BB * NHEADS), 256, 0, stream>>>(qb, kb, vT, ctx);

    gemm_bt<true, true><<<dim3(DOUT / 128, MTOT / 128), 256, 0, stream>>>(ctx, WoutT, d_out, bout, DOUT, DOUT);
}

// Round 2
// 428.526 us; speedup vs baseline: 1.3381x; 1.3381x over previous
//
#include <hip/hip_runtime.h>

#define DIN 2048
#define DOUT 2048
#define NHEADS 16
#define HDIM 128
#define LATENT 256
#define BB 2
#define SS 2048
#define MTOT (BB*SS)

using bf16 = __bf16;
using bf16x8 = __attribute__((ext_vector_type(8))) __bf16;
using f32x4 = __attribute__((ext_vector_type(4))) float;

__device__ __forceinline__ void gload16(const bf16* g, bf16* l) {
    __builtin_amdgcn_global_load_lds(
        (const __attribute__((address_space(1))) void*)g,
        (__attribute__((address_space(3))) void*)l, 16, 0, 0);
}

// ---------------- cast fp32 -> bf16 (vectorized) ----------------
__global__ void cast_f32_bf16(const float* __restrict__ in, bf16* __restrict__ out, int n) {
    int i = (blockIdx.x * blockDim.x + threadIdx.x) * 8;
    if (i >= n) return;
    float4 a = *(const float4*)(in + i);
    float4 b = *(const float4*)(in + i + 4);
    bf16x8 o;
    o[0] = (bf16)a.x; o[1] = (bf16)a.y; o[2] = (bf16)a.z; o[3] = (bf16)a.w;
    o[4] = (bf16)b.x; o[5] = (bf16)b.y; o[6] = (bf16)b.z; o[7] = (bf16)b.w;
    *(bf16x8*)(out + i) = o;
}

// ---------------- transpose + cast: W[R][C] fp32 -> WT[C][R] bf16 ----------------
__global__ void transpose_cast(const float* __restrict__ W, bf16* __restrict__ WT, int R, int C) {
    __shared__ float tile[32][33];
    int c0 = blockIdx.x * 32, r0 = blockIdx.y * 32;
    int tx = threadIdx.x & 31, ty = threadIdx.x >> 5;  // 256 threads: ty 0..7
    #pragma unroll
    for (int i = ty; i < 32; i += 8)
        tile[i][tx] = W[(size_t)(r0 + i) * C + c0 + tx];
    __syncthreads();
    #pragma unroll
    for (int i = ty; i < 32; i += 8)
        WT[(size_t)(c0 + i) * R + r0 + tx] = (bf16)tile[tx][i];
}

// ---------------- transpose v[b*S+s][h*128+d] -> vT[b][h][d][s] (bf16) ----------------
__global__ void transpose_v(const bf16* __restrict__ v, bf16* __restrict__ vT) {
    int bh = blockIdx.z;
    int s0 = blockIdx.x * 32, d0 = blockIdx.y * 32;
    __shared__ bf16 t[32][33];
    int tx = threadIdx.x & 31, ty = threadIdx.x >> 5;
    int b = bh >> 4, h = bh & 15;
    #pragma unroll
    for (int i = ty; i < 32; i += 8)
        t[i][tx] = v[(size_t)(b * SS + s0 + i) * DOUT + h * HDIM + d0 + tx];
    __syncthreads();
    #pragma unroll
    for (int i = ty; i < 32; i += 8)
        vT[((size_t)bh * HDIM + d0 + i) * SS + s0 + tx] = t[tx][i];
}

// ---------------- GEMM: C[M][N] = A[M][K] @ BT[N][K]^T (+bias) ----------------
// m97 structure: 128x128 tile, BK=32, 4 waves (2x2), global_load_lds width 16,
// linear LDS (required by global_load_lds: wave-uniform base + lane*16B).
template<bool OUT_F32, bool BIAS>
__global__ __launch_bounds__(256) void gemm_bt(const bf16* __restrict__ A,
        const bf16* __restrict__ BT, void* __restrict__ Cp,
        const float* __restrict__ bias, const int Kdim, const int Ndim) {
    const int n0 = blockIdx.x * 128, m0 = blockIdx.y * 128;
    const int tid = threadIdx.x, wave = tid >> 6, lane = tid & 63;
    const int wm = wave >> 1, wn = wave & 1;
    const int lr = lane & 15, lg = lane >> 4;
    __shared__ __align__(16) bf16 As[128][32];
    __shared__ __align__(16) bf16 Bs[128][32];
    f32x4 acc[4][4];
    #pragma unroll
    for (int i = 0; i < 4; ++i)
        #pragma unroll
        for (int j = 0; j < 4; ++j) acc[i][j] = (f32x4){0.f, 0.f, 0.f, 0.f};

    // staging: per wave, one gload16 covers 16 rows (64 lanes * 16B = 16 rows * 64B)
    const int sr = lane >> 2;          // 0..15 row within 16-row strip
    const int sc = (lane & 3) * 8;     // bf16 col 0/8/16/24
    const bf16* ga = A  + (size_t)(m0 + wave * 16 + sr) * Kdim + sc;
    const bf16* gb = BT + (size_t)(n0 + wave * 16 + sr) * Kdim + sc;
    const size_t stride64 = (size_t)64 * Kdim;
    bf16* lAd = &As[wave * 16][0];
    bf16* lBd = &Bs[wave * 16][0];

    for (int k0 = 0; k0 < Kdim; k0 += 32) {
        gload16(ga,            lAd);
        gload16(ga + stride64, lAd + 64 * 32);
        gload16(gb,            lBd);
        gload16(gb + stride64, lBd + 64 * 32);
        ga += 32; gb += 32;
        __syncthreads();
        bf16x8 af[4], bfr[4];
        #pragma unroll
        for (int i = 0; i < 4; ++i)
            af[i] = *(const bf16x8*)&As[wm * 64 + i * 16 + lr][lg * 8];
        #pragma unroll
        for (int j = 0; j < 4; ++j)
            bfr[j] = *(const bf16x8*)&Bs[wn * 64 + j * 16 + lr][lg * 8];
        #pragma unroll
        for (int i = 0; i < 4; ++i)
            #pragma unroll
            for (int j = 0; j < 4; ++j)
                acc[i][j] = __builtin_amdgcn_mfma_f32_16x16x32_bf16(af[i], bfr[j], acc[i][j], 0, 0, 0);
        __syncthreads();
    }
    #pragma unroll
    for (int i = 0; i < 4; ++i)
        #pragma unroll
        for (int j = 0; j < 4; ++j) {
            const int r0 = m0 + wm * 64 + i * 16 + lg * 4;
            const int c = n0 + wn * 64 + j * 16 + lr;
            #pragma unroll
            for (int r2 = 0; r2 < 4; ++r2) {
                float v = acc[i][j][r2];
                if (BIAS) v += bias[c];
                if (OUT_F32) ((float*)Cp)[(size_t)(r0 + r2) * Ndim + c] = v;
                else         ((bf16*)Cp)[(size_t)(r0 + r2) * Ndim + c] = (bf16)v;
            }
        }
}

// ---------------- causal flash attention, load-balanced ----------------
// grid (16, B*H); each block does q-tile bx AND q-tile 31-bx -> 33 K-tile units/block.
__global__ __launch_bounds__(256) void attn_kernel(const bf16* __restrict__ q,
        const bf16* __restrict__ k, const bf16* __restrict__ vT, bf16* __restrict__ ctx) {
    const int bh = blockIdx.y, b = bh >> 4, h = bh & 15;
    const int tid = threadIdx.x, wave = tid >> 6, lane = tid & 63;
    const int lr = lane & 15, lg = lane >> 4;
    __shared__ __align__(16) bf16 Ks[64][HDIM + 8];   // [kc][d]
    __shared__ __align__(16) bf16 Vs[HDIM][64 + 8];   // [d][kc]
    __shared__ __align__(16) bf16 Ps[64][64 + 8];     // [qr][kc], per-wave strips

    for (int half = 0; half < 2; ++half) {
        const int qt = half ? (31 - (int)blockIdx.x) : (int)blockIdx.x;
        const int q0 = qt * 64;

        bf16x8 qf[4];
        const bf16* qbase = q + ((size_t)(b * SS + q0 + wave * 16 + lr)) * DOUT + h * HDIM;
        #pragma unroll
        for (int d = 0; d < 4; ++d) qf[d] = *(const bf16x8*)(qbase + d * 32 + lg * 8);

        f32x4 o[8];
        #pragma unroll
        for (int i = 0; i < 8; ++i) o[i] = (f32x4){0.f, 0.f, 0.f, 0.f};
        float m_i[4], l_i[4];
        #pragma unroll
        for (int r = 0; r < 4; ++r) { m_i[r] = -__builtin_inff(); l_i[r] = 0.f; }
        const float scale = 0.088388347648318447f;  // 1/sqrt(128)

        const int nkt = qt + 1;
        for (int kt = 0; kt < nkt; ++kt) {
            const int kbase = kt * 64;
            {   // stage K tile (64x128) and V^T tile (128x64)
                int krow = tid >> 2, kcs = (tid & 3) * 32;
                const bf16* gk = k + ((size_t)(b * SS + kbase + krow)) * DOUT + h * HDIM + kcs;
                #pragma unroll
                for (int u = 0; u < 4; ++u)
                    *(bf16x8*)&Ks[krow][kcs + u * 8] = *(const bf16x8*)(gk + u * 8);
                int vr = tid >> 1, vcs = (tid & 1) * 32;
                const bf16* gv = vT + ((size_t)bh * HDIM + vr) * SS + kbase + vcs;
                #pragma unroll
                for (int u = 0; u < 4; ++u)
                    *(bf16x8*)&Vs[vr][vcs + u * 8] = *(const bf16x8*)(gv + u * 8);
            }
            __syncthreads();

            // S = Q @ K^T  (16 q-rows x 64 kc per wave)
            f32x4 sacc[4];
            #pragma unroll
            for (int nf = 0; nf < 4; ++nf) sacc[nf] = (f32x4){0.f, 0.f, 0.f, 0.f};
            __builtin_amdgcn_s_setprio(1);
            #pragma unroll
            for (int nf = 0; nf < 4; ++nf)
                #pragma unroll
                for (int d = 0; d < 4; ++d) {
                    bf16x8 kf = *(const bf16x8*)&Ks[nf * 16 + lr][d * 32 + lg * 8];
                    sacc[nf] = __builtin_amdgcn_mfma_f32_16x16x32_bf16(qf[d], kf, sacc[nf], 0, 0, 0);
                }
            __builtin_amdgcn_s_setprio(0);

            float sv[4][4];
            const bool maskt = (kbase + 63 > q0);  // only the diagonal tile
            #pragma unroll
            for (int nf = 0; nf < 4; ++nf)
                #pragma unroll
                for (int r = 0; r < 4; ++r) {
                    float s = sacc[nf][r] * scale;
                    if (maskt) {
                        int qr = q0 + wave * 16 + lg * 4 + r;
                        int kc = kbase + nf * 16 + lr;
                        if (qr < kc) s = -__builtin_inff();
                    }
                    sv[nf][r] = s;
                }
            // online softmax: row groups are 16 consecutive lanes (same lg)
            float corr[4];
            #pragma unroll
            for (int r = 0; r < 4; ++r) {
                float v = fmaxf(fmaxf(sv[0][r], sv[1][r]), fmaxf(sv[2][r], sv[3][r]));
                #pragma unroll
                for (int off = 1; off < 16; off <<= 1) v = fmaxf(v, __shfl_xor(v, off));
                float mnew = fmaxf(m_i[r], v);
                corr[r] = __expf(m_i[r] - mnew);
                m_i[r] = mnew;
            }
            float rsum[4] = {0.f, 0.f, 0.f, 0.f};
            #pragma unroll
            for (int nf = 0; nf < 4; ++nf)
                #pragma unroll
                for (int r = 0; r < 4; ++r) {
                    float p = __expf(sv[nf][r] - m_i[r]);
                    rsum[r] += p;
                    Ps[wave * 16 + lg * 4 + r][nf * 16 + lr] = (bf16)p;
                }
            #pragma unroll
            for (int r = 0; r < 4; ++r) {
                float v = rsum[r];
                #pragma unroll
                for (int off = 1; off < 16; off <<= 1) v += __shfl_xor(v, off);
                l_i[r] = l_i[r] * corr[r] + v;
            }
            #pragma unroll
            for (int df = 0; df < 8; ++df)
                #pragma unroll
                for (int r = 0; r < 4; ++r) o[df][r] *= corr[r];

            // O += P @ V   (P from own wave's LDS strip; intra-wave ds ordering suffices)
            __builtin_amdgcn_s_setprio(1);
            #pragma unroll
            for (int ks = 0; ks < 2; ++ks) {
                bf16x8 pf = *(const bf16x8*)&Ps[wave * 16 + lr][ks * 32 + lg * 8];
                #pragma unroll
                for (int df = 0; df < 8; ++df) {
                    bf16x8 vf = *(const bf16x8*)&Vs[df * 16 + lr][ks * 32 + lg * 8];
                    o[df] = __builtin_amdgcn_mfma_f32_16x16x32_bf16(pf, vf, o[df], 0, 0, 0);
                }
            }
            __builtin_amdgcn_s_setprio(0);
            __syncthreads();
        }

        #pragma unroll
        for (int df = 0; df < 8; ++df)
            #pragma unroll
            for (int r = 0; r < 4; ++r) {
                int rrow = q0 + wave * 16 + lg * 4 + r;
                int col = h * HDIM + df * 16 + lr;
                ctx[(size_t)(b * SS + rrow) * DOUT + col] = (bf16)(o[df][r] / l_i[r]);
            }
    }
}

extern "C" void kernel_launch(void* const* d_in, const int* in_sizes, int n_in,
                              void* d_out, int out_size, void* d_ws, size_t ws_size,
                              hipStream_t stream) {
    const float* x    = (const float*)d_in[0];
    const float* Wq   = (const float*)d_in[1];
    const float* Wdkv = (const float*)d_in[2];
    const float* Wuk  = (const float*)d_in[3];
    const float* Wuv  = (const float*)d_in[4];
    const float* Wout = (const float*)d_in[5];
    const float* bout = (const float*)d_in[6];

    char* ws = (char*)d_ws;
    size_t off = 0;
    auto alloc = [&](size_t bytes) { char* p = ws + off; off = (off + bytes + 255) & ~255ULL; return p; };
    bf16* xb    = (bf16*)alloc((size_t)MTOT * DIN * 2);
    bf16* WqT   = (bf16*)alloc((size_t)DOUT * DIN * 2);
    bf16* WdkvT = (bf16*)alloc((size_t)LATENT * DIN * 2);
    bf16* WukT  = (bf16*)alloc((size_t)DOUT * LATENT * 2);
    bf16* WuvT  = (bf16*)alloc((size_t)DOUT * LATENT * 2);
    bf16* WoutT = (bf16*)alloc((size_t)DOUT * DOUT * 2);
    bf16* qb    = (bf16*)alloc((size_t)MTOT * DOUT * 2);
    bf16* lat   = (bf16*)alloc((size_t)MTOT * LATENT * 2);
    bf16* kb    = (bf16*)alloc((size_t)MTOT * DOUT * 2);
    bf16* vb    = (bf16*)alloc((size_t)MTOT * DOUT * 2);
    bf16* vT    = (bf16*)alloc((size_t)BB * NHEADS * HDIM * SS * 2);
    bf16* ctx   = (bf16*)alloc((size_t)MTOT * DOUT * 2);

    cast_f32_bf16<<<(MTOT * DIN) / 8 / 256, 256, 0, stream>>>(x, xb, MTOT * DIN);
    transpose_cast<<<dim3(DOUT / 32, DIN / 32), 256, 0, stream>>>(Wq, WqT, DIN, DOUT);
    transpose_cast<<<dim3(LATENT / 32, DIN / 32), 256, 0, stream>>>(Wdkv, WdkvT, DIN, LATENT);
    transpose_cast<<<dim3(DOUT / 32, LATENT / 32), 256, 0, stream>>>(Wuk, WukT, LATENT, DOUT);
    transpose_cast<<<dim3(DOUT / 32, LATENT / 32), 256, 0, stream>>>(Wuv, WuvT, LATENT, DOUT);
    transpose_cast<<<dim3(DOUT / 32, DOUT / 32), 256, 0, stream>>>(Wout, WoutT, DOUT, DOUT);

    gemm_bt<false, false><<<dim3(DOUT / 128, MTOT / 128), 256, 0, stream>>>(xb, WqT, qb, nullptr, DIN, DOUT);
    gemm_bt<false, false><<<dim3(LATENT / 128, MTOT / 128), 256, 0, stream>>>(xb, WdkvT, lat, nullptr, DIN, LATENT);
    gemm_bt<false, false><<<dim3(DOUT / 128, MTOT / 128), 256, 0, stream>>>(lat, WukT, kb, nullptr, LATENT, DOUT);
    gemm_bt<false, false><<<dim3(DOUT / 128, MTOT / 128), 256, 0, stream>>>(lat, WuvT, vb, nullptr, LATENT, DOUT);

    transpose_v<<<dim3(SS / 32, HDIM / 32, BB * NHEADS), 256, 0, stream>>>(vb, vT);

    attn_kernel<<<dim3(16, BB * NHEADS), 256, 0, stream>>>(qb, kb, vT, ctx);

    gemm_bt<true, true><<<dim3(DOUT / 128, MTOT / 128), 256, 0, stream>>>(ctx, WoutT, d_out, bout, DOUT, DOUT);
}